// Round 2
// baseline (2110.612 us; speedup 1.0000x reference)
//
#include <hip/hip_runtime.h>

// FeedBack LSTM: B=1024, T_in=128, F=3, UNITS=256, out_steps=32.
// R2: 64 blocks x 1024 threads (16 waves). Each block owns 16 batch rows.
// ALL of Wr (+Wk folded in as k-tile 8) lives in REGISTERS: wave w holds the
// B-fragments for columns {q*256 + w*16 .. +15}, q=0..3 -> 36 half8 = 144 VGPR.
// Per step: 8x ds_read_b128 (h A-frags) + 36 reg-resident MFMA + in-lane gate
// math + 4x ds_write_b16. Zero global traffic in the recurrence loop.

#define TIN     128
#define FIN     3
#define UNITS   256
#define OSTEPS  32
#define ROWS    16
#define THREADS 1024
#define NKT     9          // 8 k-tiles of h (256) + 1 k-tile carrying x (Wk)

typedef float    f32x4 __attribute__((ext_vector_type(4)));
typedef _Float16 half8 __attribute__((ext_vector_type(8)));

__device__ __forceinline__ float fast_rcp(float x) { return __builtin_amdgcn_rcpf(x); }
__device__ __forceinline__ float sigm(float x)  { return fast_rcp(1.0f + __expf(-x)); }
__device__ __forceinline__ float tanh_f(float x){ return 1.0f - 2.0f * fast_rcp(__expf(2.0f * x) + 1.0f); }

// Pack [Wr; Wk; 0-pad] (288 x 1024, fp32) -> fp16 B-fragments.
// P[((ct*9 + kt)*64 + lane)*8 + j] = W[kt*32 + (lane>>4)*8 + j][ct*16 + (lane&15)]
// where W rows 0..255 = Wr, rows 256..258 = Wk, rows 259..287 = 0.
__global__ __launch_bounds__(512) void pack_wr(const float* __restrict__ Wr,
                                               const float* __restrict__ Wk,
                                               _Float16* __restrict__ P)
{
    int idx = blockIdx.x * 512 + threadIdx.x;      // 64 ct * 9 kt * 64 lanes = 36864
    int l   = idx & 63;
    int kt  = (idx >> 6) % NKT;
    int ct  = (idx >> 6) / NKT;
    int g = l >> 4, n = l & 15;
    int col = ct * 16 + n;
    half8 v;
#pragma unroll
    for (int j = 0; j < 8; ++j) {
        int k = kt * 32 + g * 8 + j;
        float val;
        if (k < 256)            val = Wr[k * 1024 + col];
        else if (k < 256 + FIN) val = Wk[(k - 256) * 1024 + col];
        else                    val = 0.0f;
        v[j] = (_Float16)val;
    }
    *reinterpret_cast<half8*>(P + (size_t)idx * 8) = v;
}

__global__ __launch_bounds__(THREADS) void lstm_fused(
    const float* __restrict__ x_in,   // [1024][128][3]
    const float* __restrict__ bias,   // [1024]
    const float* __restrict__ Wd,     // [256][3]
    const float* __restrict__ bd,     // [3]
    const _Float16* __restrict__ WrP, // packed fragments (see pack_wr)
    float* __restrict__ out)          // [1024][32][3]
{
    // h in A-fragment order: hp[buf][kt*512 + l*8 + j] = h[l&15][kt*32+(l>>4)*8+j]
    __shared__ alignas(16) _Float16 hp[2][8 * 512];            // 2 x 8 KB
    __shared__ alignas(16) float    xs_t[TIN * ROWS * FIN];    // [t][m][f], 24 KB
    __shared__ alignas(16) float    h_plain[ROWS][UNITS + 4];  // fp32 h (decode head)
    __shared__ float                pred_buf[ROWS][FIN];       // fed-back prediction

    const int tid  = threadIdx.x;
    const int w    = tid >> 6;     // wave 0..15: owns units [w*16, w*16+16) x 4 gates
    const int l    = tid & 63;
    const int g    = l >> 4;
    const int n    = l & 15;
    const int blk  = blockIdx.x;   // batch rows [blk*16, blk*16+16)
    const int row0 = g * 4;        // MFMA C-layout rows for this lane

    // ---- prologue ----
    const float* xsrc = x_in + (size_t)blk * ROWS * TIN * FIN;
    for (int i = tid; i < ROWS * TIN * FIN; i += THREADS) {
        int m   = i / (TIN * FIN);
        int rem = i - m * (TIN * FIN);
        int t   = rem / FIN;
        int f   = rem - t * FIN;
        xs_t[(t * ROWS + m) * FIN + f] = xsrc[i];   // transposed: conflict-free reads
    }
    for (int i = tid; i < 8 * 512; i += THREADS) hp[0][i] = (_Float16)0.0f;

    // persistent B-fragments: bfr[q][kt], ct = q*16 + w
    half8 bfr[4][NKT];
#pragma unroll
    for (int q = 0; q < 4; ++q) {
        int ct = q * 16 + w;
#pragma unroll
        for (int kt = 0; kt < NKT; ++kt)
            bfr[q][kt] = *reinterpret_cast<const half8*>(
                WrP + ((size_t)(ct * NKT + kt) * 64 + l) * 8);
    }

    float b_r[4];
#pragma unroll
    for (int q = 0; q < 4; ++q) b_r[q] = bias[q * 256 + w * 16 + n];

    float wd_r[4][3];
#pragma unroll
    for (int j = 0; j < 4; ++j)
#pragma unroll
        for (int f = 0; f < 3; ++f) wd_r[j][f] = Wd[(4 * l + j) * 3 + f];
    float bd_r[3];
#pragma unroll
    for (int f = 0; f < 3; ++f) bd_r[f] = bd[f];

    float c_st[4];
#pragma unroll
    for (int r = 0; r < 4; ++r) c_st[r] = 0.0f;

    const int u    = w * 16 + n;                       // unit this lane owns
    const int base = (u >> 5) * 512 + ((u >> 3) & 3) * 128 + (u & 7);

    __syncthreads();

    int cur = 0;
    for (int t = 0; t < TIN + OSTEPS - 1; ++t) {       // 159 sequential cell steps
        const bool dec      = (t >= TIN);
        const bool wr_plain = (t >= TIN - 1);

        // A-fragments: 8 from LDS (h), 1 built from x / fed-back pred
        half8 a[NKT];
        const _Float16* hpc = hp[cur];
#pragma unroll
        for (int kt = 0; kt < 8; ++kt)
            a[kt] = *reinterpret_cast<const half8*>(hpc + kt * 512 + l * 8);
        half8 a8 = {};
        if (g == 0) {                                  // k = 256..258 live here
            float x0, x1, x2;
            if (dec) {
                x0 = pred_buf[n][0]; x1 = pred_buf[n][1]; x2 = pred_buf[n][2];
            } else {
                const float* xp = &xs_t[(t * ROWS + n) * FIN];
                x0 = xp[0]; x1 = xp[1]; x2 = xp[2];
            }
            a8[0] = (_Float16)x0; a8[1] = (_Float16)x1; a8[2] = (_Float16)x2;
        }
        a[8] = a8;

        f32x4 acc[4];
#pragma unroll
        for (int q = 0; q < 4; ++q)
#pragma unroll
            for (int r = 0; r < 4; ++r) acc[q][r] = b_r[q];

#pragma unroll
        for (int kt = 0; kt < NKT; ++kt)
#pragma unroll
            for (int q = 0; q < 4; ++q)
                acc[q] = __builtin_amdgcn_mfma_f32_16x16x32_f16(a[kt], bfr[q][kt], acc[q], 0, 0, 0);

        // gates (all in-lane: q0..3 = i,f,g,o of unit u), state update, h write
        const int nxt = cur ^ 1;
#pragma unroll
        for (int r = 0; r < 4; ++r) {
            float iv = sigm(acc[0][r]);
            float fv = sigm(acc[1][r]);
            float gv = tanh_f(acc[2][r]);
            float ov = sigm(acc[3][r]);
            float cc = fv * c_st[r] + iv * gv;
            c_st[r] = cc;
            float hv = ov * tanh_f(cc);
            hp[nxt][base + (row0 + r) * 8] = (_Float16)hv;
            if (wr_plain) h_plain[row0 + r][u] = hv;
        }
        __syncthreads();

        // decode head: wave w reduces batch-row w (pred = h @ Wd + bd, fp32)
        if (wr_plain) {
            int s   = t - (TIN - 1);
            int row = w;
            const float4 hv4 = *reinterpret_cast<const float4*>(&h_plain[row][4 * l]);
            float p0 = hv4.x * wd_r[0][0] + hv4.y * wd_r[1][0] + hv4.z * wd_r[2][0] + hv4.w * wd_r[3][0];
            float p1 = hv4.x * wd_r[0][1] + hv4.y * wd_r[1][1] + hv4.z * wd_r[2][1] + hv4.w * wd_r[3][1];
            float p2 = hv4.x * wd_r[0][2] + hv4.y * wd_r[1][2] + hv4.z * wd_r[2][2] + hv4.w * wd_r[3][2];
#pragma unroll
            for (int off = 32; off > 0; off >>= 1) {
                p0 += __shfl_xor(p0, off);
                p1 += __shfl_xor(p1, off);
                p2 += __shfl_xor(p2, off);
            }
            if (l == 0) {
                float o0 = p0 + bd_r[0], o1 = p1 + bd_r[1], o2 = p2 + bd_r[2];
                pred_buf[row][0] = o0; pred_buf[row][1] = o1; pred_buf[row][2] = o2;
                float* op = out + (((size_t)blk * ROWS + row) * OSTEPS + s) * 3;
                op[0] = o0; op[1] = o1; op[2] = o2;
            }
            __syncthreads();
        }
        cur ^= 1;
    }
}

extern "C" void kernel_launch(void* const* d_in, const int* in_sizes, int n_in,
                              void* d_out, int out_size, void* d_ws, size_t ws_size,
                              hipStream_t stream)
{
    const float* x  = (const float*)d_in[0];
    const float* Wk = (const float*)d_in[1];
    const float* Wr = (const float*)d_in[2];
    const float* b  = (const float*)d_in[3];
    const float* Wd = (const float*)d_in[4];
    const float* bd = (const float*)d_in[5];
    _Float16* WrP = (_Float16*)d_ws;            // 576 KB packed (Wr + Wk) fragments
    float* out = (float*)d_out;

    pack_wr<<<72, 512, 0, stream>>>(Wr, Wk, WrP);
    lstm_fused<<<64, THREADS, 0, stream>>>(x, b, Wd, bd, WrP, out);
}

// Round 3
// 1721.861 us; speedup vs baseline: 1.2258x; 1.2258x over previous
//
#include <hip/hip_runtime.h>

// FeedBack LSTM: B=1024, T_in=128, F=3, UNITS=256, out_steps=32.
// R3: 64 blocks x 1024 threads (16 waves), each block owns 16 batch rows.
// Weights stream from L2 every step (they cannot fit in LDS/VGPR: fp16 Wr =
// 512 KB = whole CU register file -- R2's spill disaster). Fixes vs R1:
//  - 16 waves (4/SIMD) instead of 8 (2/SIMD): 2x latency hiding
//  - per-(block,wave) k-tile rotation de-lockstep: 64 blocks no longer read
//    identical L2 addresses in the same cycle (L2 channel serialization)
//  - depth-2 prefetch with static 3-slot pipeline (fully unrolled)
//  - x@Wk via VALU (no streamed zero-padded k-tile)

#define TIN     128
#define FIN     3
#define UNITS   256
#define OSTEPS  32
#define ROWS    16
#define THREADS 1024
#define NKT     8

typedef float    f32x4 __attribute__((ext_vector_type(4)));
typedef _Float16 half8 __attribute__((ext_vector_type(8)));

__device__ __forceinline__ float fast_rcp(float x) { return __builtin_amdgcn_rcpf(x); }
__device__ __forceinline__ float sigm(float x)  { return fast_rcp(1.0f + __expf(-x)); }
__device__ __forceinline__ float tanh_f(float x){ return 1.0f - 2.0f * fast_rcp(__expf(2.0f * x) + 1.0f); }

// Pack Wr [256][1024] fp32 -> fp16 B-fragments:
// P[ct*4096 + kt*512 + l*8 + j] = Wr[kt*32 + (l>>4)*8 + j][ct*16 + (l&15)]
__global__ __launch_bounds__(512) void pack_wr(const float* __restrict__ Wr,
                                               _Float16* __restrict__ P)
{
    int idx = blockIdx.x * 512 + threadIdx.x;   // (ct*8 + kt)*64 + l, 32768 total
    int l   = idx & 63;
    int kt  = (idx >> 6) & 7;
    int ct  = idx >> 9;
    int g = l >> 4, n = l & 15;
    int col = ct * 16 + n;
    int k0  = kt * 32 + g * 8;
    half8 v;
#pragma unroll
    for (int j = 0; j < 8; ++j) v[j] = (_Float16)Wr[(k0 + j) * 1024 + col];
    *reinterpret_cast<half8*>(P + (size_t)idx * 8) = v;
}

__global__ __launch_bounds__(THREADS) void lstm_fused(
    const float* __restrict__ x_in,   // [1024][128][3]
    const float* __restrict__ Wk,     // [3][1024]
    const float* __restrict__ bias,   // [1024]
    const float* __restrict__ Wd,     // [256][3]
    const float* __restrict__ bd,     // [3]
    const _Float16* __restrict__ WrP, // packed Wr fragments
    float* __restrict__ out)          // [1024][32][3]
{
    // h in A-fragment order: hp[buf][kt*512 + l*8 + j] = h[l&15][kt*32+(l>>4)*8+j]
    __shared__ alignas(16) _Float16 hp[2][8 * 512];            // 2 x 8 KB
    __shared__ alignas(16) float    xs[ROWS * TIN * FIN];      // 24 KB staged inputs
    __shared__ alignas(16) float    h_plain[ROWS][UNITS + 4];  // fp32 h (decode head)
    __shared__ float                pred_buf[ROWS][FIN];       // fed-back prediction

    const int tid  = threadIdx.x;
    const int w    = tid >> 6;     // wave 0..15: owns units [w*16, w*16+16) x 4 gates
    const int l    = tid & 63;
    const int g    = l >> 4;
    const int n    = l & 15;
    const int blk  = blockIdx.x;   // batch rows [blk*16, blk*16+16)
    const int row0 = g * 4;        // MFMA C-layout rows for this lane

    // ---- prologue ----
    const float* xsrc = x_in + (size_t)blk * ROWS * TIN * FIN;
    for (int i = tid; i < ROWS * TIN * FIN; i += THREADS) xs[i] = xsrc[i];
    for (int i = tid; i < 8 * 512; i += THREADS) hp[0][i] = (_Float16)0.0f;

    const int u = w * 16 + n;                  // unit this lane owns
    float b_r[4], wk_r[4][3];
    int   wb[4];
#pragma unroll
    for (int q = 0; q < 4; ++q) {              // q = gate (i,f,g,o)
        int col = q * 256 + u;
        b_r[q] = bias[col];
#pragma unroll
        for (int f = 0; f < 3; ++f) wk_r[q][f] = Wk[f * 1024 + col];
        wb[q] = (q * 16 + w) * 4096 + l * 8;   // frag base (elements) for ct=q*16+w
    }
    const int base = (u >> 5) * 512 + ((u >> 3) & 3) * 128 + (u & 7);
    const int kt0  = (blk + 3 * w) & 7;        // de-lockstep rotation phase

    float c_st[4];
#pragma unroll
    for (int r = 0; r < 4; ++r) c_st[r] = 0.0f;

    __syncthreads();

    int cur = 0;
    for (int t = 0; t < TIN + OSTEPS - 1; ++t) {   // 159 sequential cell steps
        const bool dec      = (t >= TIN);
        const bool wr_plain = (t >= TIN - 1);

        // x for this step (fp32): staged input or fed-back prediction
        float xv[4][3];
#pragma unroll
        for (int r = 0; r < 4; ++r) {
            int row = row0 + r;
            if (dec) {
                xv[r][0] = pred_buf[row][0];
                xv[r][1] = pred_buf[row][1];
                xv[r][2] = pred_buf[row][2];
            } else {
                const float* xp = &xs[(row * TIN + t) * 3];
                xv[r][0] = xp[0]; xv[r][1] = xp[1]; xv[r][2] = xp[2];
            }
        }

        // z init = b + x@Wk (fp32, MFMA C-layout)
        f32x4 acc[4];
#pragma unroll
        for (int q = 0; q < 4; ++q)
#pragma unroll
            for (int r = 0; r < 4; ++r)
                acc[q][r] = b_r[q] + xv[r][0] * wk_r[q][0] + xv[r][1] * wk_r[q][1]
                          + xv[r][2] * wk_r[q][2];

        // z += h @ Wr : 8 k-tiles, rotated start, depth-2 prefetch (3 slots)
        const _Float16* hpc = hp[cur];
        half8 As[3];
        half8 Bs[3][4];
        {
            int k = kt0;
            As[0] = *reinterpret_cast<const half8*>(hpc + k * 512 + l * 8);
#pragma unroll
            for (int q = 0; q < 4; ++q)
                Bs[0][q] = *reinterpret_cast<const half8*>(WrP + wb[q] + k * 512);
        }
        {
            int k = (kt0 + 1) & 7;
            As[1] = *reinterpret_cast<const half8*>(hpc + k * 512 + l * 8);
#pragma unroll
            for (int q = 0; q < 4; ++q)
                Bs[1][q] = *reinterpret_cast<const half8*>(WrP + wb[q] + k * 512);
        }
#pragma unroll
        for (int i = 0; i < 8; ++i) {
            const int s  = i % 3;            // static after unroll (no scratch)
            const int sn = (i + 2) % 3;
            if (i < 6) {
                int k = (kt0 + i + 2) & 7;
                As[sn] = *reinterpret_cast<const half8*>(hpc + k * 512 + l * 8);
#pragma unroll
                for (int q = 0; q < 4; ++q)
                    Bs[sn][q] = *reinterpret_cast<const half8*>(WrP + wb[q] + k * 512);
            }
#pragma unroll
            for (int q = 0; q < 4; ++q)
                acc[q] = __builtin_amdgcn_mfma_f32_16x16x32_f16(As[s], Bs[s][q], acc[q], 0, 0, 0);
        }

        // gates (all in-lane), state update, h write in A-frag order
        const int nxt = cur ^ 1;
#pragma unroll
        for (int r = 0; r < 4; ++r) {
            float iv = sigm(acc[0][r]);
            float fv = sigm(acc[1][r]);
            float gv = tanh_f(acc[2][r]);
            float ov = sigm(acc[3][r]);
            float cc = fv * c_st[r] + iv * gv;
            c_st[r] = cc;
            float hv = ov * tanh_f(cc);
            hp[nxt][base + (row0 + r) * 8] = (_Float16)hv;
            if (wr_plain) h_plain[row0 + r][u] = hv;
        }
        __syncthreads();

        // decode head: wave w reduces batch-row w (pred = h @ Wd + bd, fp32)
        if (wr_plain) {
            int s   = t - (TIN - 1);
            int row = w;
            const float4 hv4 = *reinterpret_cast<const float4*>(&h_plain[row][4 * l]);
            float p0 = 0.0f, p1 = 0.0f, p2 = 0.0f;
#pragma unroll
            for (int j = 0; j < 4; ++j) {
                const float* wdp = Wd + (4 * l + j) * 3;     // L2-hot after step 1
                float hj = (j == 0) ? hv4.x : (j == 1) ? hv4.y : (j == 2) ? hv4.z : hv4.w;
                p0 += hj * wdp[0];
                p1 += hj * wdp[1];
                p2 += hj * wdp[2];
            }
#pragma unroll
            for (int off = 32; off > 0; off >>= 1) {
                p0 += __shfl_xor(p0, off);
                p1 += __shfl_xor(p1, off);
                p2 += __shfl_xor(p2, off);
            }
            if (l == 0) {
                float o0 = p0 + bd[0], o1 = p1 + bd[1], o2 = p2 + bd[2];
                pred_buf[row][0] = o0; pred_buf[row][1] = o1; pred_buf[row][2] = o2;
                float* op = out + (((size_t)blk * ROWS + row) * OSTEPS + s) * 3;
                op[0] = o0; op[1] = o1; op[2] = o2;
            }
            __syncthreads();
        }
        cur ^= 1;
    }
}

extern "C" void kernel_launch(void* const* d_in, const int* in_sizes, int n_in,
                              void* d_out, int out_size, void* d_ws, size_t ws_size,
                              hipStream_t stream)
{
    const float* x  = (const float*)d_in[0];
    const float* Wk = (const float*)d_in[1];
    const float* Wr = (const float*)d_in[2];
    const float* b  = (const float*)d_in[3];
    const float* Wd = (const float*)d_in[4];
    const float* bd = (const float*)d_in[5];
    _Float16* WrP = (_Float16*)d_ws;            // 512 KB packed recurrent weights
    float* out = (float*)d_out;

    pack_wr<<<64, 512, 0, stream>>>(Wr, WrP);
    lstm_fused<<<64, THREADS, 0, stream>>>(x, Wk, b, Wd, bd, WrP, out);
}